// Round 7
// baseline (1558.897 us; speedup 1.0000x reference)
//
#include <hip/hip_runtime.h>
#include <hip/hip_bf16.h>
#include <math.h>

// VectorQuantizer: X[32768,256] f32, W[4096,256] f32
// out = [quantized_st (32768*256 f32), loss (1 f32)]
// Pass 1: bf16 MFMA GEMM (Xh.Wh) -> per-(token,tile) d2' min
// Cand:   per-token thr = gmin' + (sqrt(x_sq)*7e-5 + 3.2e-4)  [>= 2E rigorous]
// Pass 2a (vq_exact2): gathered bf16 MFMA on candidate tiles, emit per-CODE
//          pairs with d2' <= thr (bitwise same d2' as pass 1)
// Pass 2b (vq_dots): exact sequential f32 dot per pair (validated rounding),
//          packed atomicMin winner (min d2, then lowest index)
#define NTOK 32768
#define NCODE 4096
#define DIM 256
#define NT 32        // code tiles of 128
#define PAIR_CAP 2300000

typedef short bf16x8 __attribute__((ext_vector_type(8)));
typedef float f32x16 __attribute__((ext_vector_type(16)));

// ---- big-ws layout (bytes), total 46,269,696 (<= 46,612,736 known-OK) ----
#define OFF_XH 0u            // bf16[32768*256]
#define OFF_WH 16777216u     // bf16[4096*256]
#define OFF_SUMS 18874368u   // f32[36864]
#define OFF_PART 19021824u   // f32[32768][32]
#define OFF_THR 23216128u    // f32[32768]
#define OFF_CNT 23347200u    // int[64]: [0..31] tile counts, [32] paircnt
#define OFF_LIST 23347456u   // int[32][32768]
#define OFF_PAIRS 27541760u  // u32[2,300,000]
#define OFF_WIN 36741760u    // u64[32768] (8-aligned)
#define OFF_LPART 37003904u  // double[8192]
#define WS_NEEDED 37069440ull
// ---- small-ws (fallback, validated round 2) ----
#define OFF_SUMS_O 0u
#define OFF_PART_O 147456u
#define OFF_LPART_O 8536064u

__device__ __forceinline__ void gload16(const void* g, void* l) {
  __builtin_amdgcn_global_load_lds(
      (const __attribute__((address_space(1))) void*)g,
      (__attribute__((address_space(3))) void*)l, 16, 0, 0);
}
__device__ __forceinline__ unsigned short bfh(float f) {
  __hip_bfloat16 h = __float2bfloat16(f);
  return *reinterpret_cast<unsigned short*>(&h);
}

// ---------------- prep: sums (+ bf16 conversion, + zero counters) -----------
__global__ __launch_bounds__(256) void vq_prep(
    const float* __restrict__ X, const float* __restrict__ W,
    float* __restrict__ sums, unsigned short* __restrict__ xh,
    unsigned short* __restrict__ wh, int* __restrict__ cnt, int conv) {
  const int tid = threadIdx.x;
  if (conv && blockIdx.x == 0 && tid < NT + 1) cnt[tid] = 0;
  const int wave = tid >> 6, lane = tid & 63;
  const int row = blockIdx.x * 4 + wave;  // 0..36863
  const bool isx = row < NTOK;
  const float* src = isx ? (X + (size_t)row * DIM)
                         : (W + (size_t)(row - NTOK) * DIM);
  float4 v = reinterpret_cast<const float4*>(src)[lane];
  float s = v.x * v.x + v.y * v.y + v.z * v.z + v.w * v.w;
#pragma unroll
  for (int m = 1; m < 64; m <<= 1) s += __shfl_xor(s, m, 64);
  if (lane == 0) sums[row] = s;
  if (conv) {
    ushort4 hi = make_ushort4(bfh(v.x), bfh(v.y), bfh(v.z), bfh(v.w));
    const int r = isx ? row : row - NTOK;
    unsigned short* dh = isx ? xh : wh;
    ((ushort4*)(dh + (size_t)r * DIM))[lane] = hi;
  }
}

// ---------------- pass 1: bf16 MFMA GEMM (K=256) + per-tile d2' min ---------
// Grid 8192 = 256 mblk x 32 nblk. 256 thr = 4 waves (2x2), wave tile 64x64.
__global__ __launch_bounds__(256, 2) void vq_mfma(
    const unsigned short* __restrict__ xh, const unsigned short* __restrict__ wh,
    const float* __restrict__ sums, float* __restrict__ part) {
  __shared__ short lds[2][2][8192];  // [dbuf][A/B][128 rows x 64 bf16] = 64 KB
  const int tid = threadIdx.x;
  const int wave = tid >> 6, lane = tid & 63;
  const int wr = wave >> 1, wc = wave & 1;
  const int half = lane >> 5, l31 = lane & 31;
  const int nblk = blockIdx.x & (NT - 1);
  const int mbase = (blockIdx.x >> 5) * 128, nbase = nblk * 128;

  f32x16 acc00, acc01, acc10, acc11;
#pragma unroll
  for (int i = 0; i < 16; ++i) {
    acc00[i] = 0.f; acc01[i] = 0.f; acc10[i] = 0.f; acc11[i] = 0.f;
  }

  auto stage = [&](int buf, int kt) {
    const int k0 = kt * 64;
#pragma unroll
    for (int it = 0; it < 4; ++it) {
      int L = it * 256 + tid;          // 16B-chunk id 0..1023 (8 chunks/row)
      int row = L >> 3, cc = L & 7;
      int off = k0 + ((cc ^ (row & 7)) << 3);
      gload16(xh + (size_t)(mbase + row) * DIM + off, &lds[buf][0][L << 3]);
    }
#pragma unroll
    for (int it = 0; it < 4; ++it) {
      int L = it * 256 + tid;
      int row = L >> 3, cc = L & 7;
      int off = k0 + ((cc ^ (row & 7)) << 3);
      gload16(wh + (size_t)(nbase + row) * DIM + off, &lds[buf][1][L << 3]);
    }
  };
  auto frag = [&](const short* b, int row, int kc) -> bf16x8 {
    return *(const bf16x8*)(b + row * 64 + ((kc ^ (row & 7)) << 3));
  };
  auto compute = [&](int buf) {
    const short* As = lds[buf][0];
    const short* Bs = lds[buf][1];
    const int r0 = wr * 64 + l31, r1 = r0 + 32;
    const int c0 = wc * 64 + l31, c1 = c0 + 32;
#pragma unroll
    for (int ks = 0; ks < 4; ++ks) {
      const int kc = ks * 2 + half;
      bf16x8 a0 = frag(As, r0, kc), a1 = frag(As, r1, kc);
      bf16x8 b0 = frag(Bs, c0, kc), b1 = frag(Bs, c1, kc);
      acc00 = __builtin_amdgcn_mfma_f32_32x32x16_bf16(a0, b0, acc00, 0, 0, 0);
      acc01 = __builtin_amdgcn_mfma_f32_32x32x16_bf16(a0, b1, acc01, 0, 0, 0);
      acc10 = __builtin_amdgcn_mfma_f32_32x32x16_bf16(a1, b0, acc10, 0, 0, 0);
      acc11 = __builtin_amdgcn_mfma_f32_32x32x16_bf16(a1, b1, acc11, 0, 0, 0);
    }
  };

  stage(0, 0);
  __syncthreads();
  for (int kt = 0; kt < 4; ++kt) {
    const int cur = kt & 1;
    if (kt < 3) stage(cur ^ 1, kt + 1);
    compute(cur);
    __syncthreads();
  }

  float* redm = (float*)lds;  // [128][2]
  const float wq0 = sums[NTOK + nbase + wc * 64 + l31];
  const float wq1 = sums[NTOK + nbase + wc * 64 + l31 + 32];
  auto epi = [&](int mf, const f32x16& A0, const f32x16& A1) {
#pragma unroll
    for (int reg = 0; reg < 16; ++reg) {
      int rl = wr * 64 + mf * 32 + (reg & 3) + ((reg >> 2) << 3) + (half << 2);
      float xs = sums[mbase + rl];
      float d0 = fmaf(-2.f, A0[reg], xs) + wq0;
      float d1 = fmaf(-2.f, A1[reg], xs) + wq1;
      float v = fminf(d0, d1);
#pragma unroll
      for (int m = 1; m <= 16; m <<= 1) v = fminf(v, __shfl_xor(v, m, 64));
      if (l31 == 0) redm[rl * 2 + wc] = v;
    }
  };
  epi(0, acc00, acc01);
  epi(1, acc10, acc11);
  __syncthreads();
  if (tid < 128)
    part[(size_t)(mbase + tid) * NT + nblk] = fminf(redm[tid * 2], redm[tid * 2 + 1]);
}

// ------- cand: per-token thr (rigorous 2E bound) + candidate tiles ----------
__global__ __launch_bounds__(256) void vq_cand(
    const float* __restrict__ part, const float* __restrict__ sums,
    float* __restrict__ thr, int* __restrict__ cnt, int* __restrict__ list,
    unsigned long long* __restrict__ winner) {
  const int t = blockIdx.x * 256 + threadIdx.x;
  const int lane = threadIdx.x & 63;
  const float* p = part + (size_t)t * NT;
  float g = p[0];
#pragma unroll
  for (int i = 1; i < NT; ++i) g = fminf(g, p[i]);
  winner[t] = ~0ull;
  // 2E <= sqrt(x_sq)*6.1e-5 + 2.6e-4; use 7e-5/3.2e-4 (~15% headroom)
  const float th = g + fmaf(sqrtf(sums[t]), 7.0e-5f, 3.2e-4f);
  thr[t] = th;
#pragma unroll 1
  for (int tau = 0; tau < NT; ++tau) {
    bool take = p[tau] <= th;
    unsigned long long mask = __ballot(take);
    if (mask) {
      int leader = __ffsll((unsigned long long)mask) - 1;
      int nw = __popcll(mask);
      int base = 0;
      if (lane == leader) base = atomicAdd(&cnt[tau], nw);
      base = __shfl(base, leader, 64);
      if (take) {
        int pre = __popcll(mask & ((1ull << lane) - 1));
        list[tau * NTOK + base + pre] = t;
      }
    }
  }
}

// ------- pass 2a: gathered bf16 MFMA on candidate tiles, emit per-code pairs
// d2' here is bitwise identical to pass 1 (same fragments, same K order).
__global__ __launch_bounds__(256, 2) void vq_exact2(
    const unsigned short* __restrict__ xh, const unsigned short* __restrict__ wh,
    const float* __restrict__ sums, const float* __restrict__ thr,
    const int* __restrict__ cnt, const int* __restrict__ list,
    unsigned int* __restrict__ pairs, int* __restrict__ paircnt) {
  __shared__ short lds[2][2][8192];
  __shared__ int ids[128];
  const int tid = threadIdx.x;
  const int wave = tid >> 6, lane = tid & 63;
  const int wr = wave >> 1, wc = wave & 1;
  const int half = lane >> 5, l31 = lane & 31;
  const int tau = blockIdx.x >> 5, slot = blockIdx.x & 31;  // 32 slots/tile
  const int count = cnt[tau];
  const int nbase = tau * 128;
  const int c0 = nbase + wc * 64 + l31, c1 = c0 + 32;
  const float wq0 = sums[NTOK + c0], wq1 = sums[NTOK + c1];

  for (int base = slot * 128; base < count; base += 4096) {
    __syncthreads();
    if (tid < 128) ids[tid] = list[tau * NTOK + min(base + tid, count - 1)];
    __syncthreads();
    f32x16 acc00, acc01, acc10, acc11;
#pragma unroll
    for (int i = 0; i < 16; ++i) {
      acc00[i] = 0.f; acc01[i] = 0.f; acc10[i] = 0.f; acc11[i] = 0.f;
    }
    auto stage = [&](int buf, int kt) {
      const int k0 = kt * 64;
#pragma unroll
      for (int it = 0; it < 4; ++it) {
        int L = it * 256 + tid;
        int row = L >> 3, cc = L & 7;
        int off = k0 + ((cc ^ (row & 7)) << 3);
        gload16(xh + (size_t)ids[row] * DIM + off, &lds[buf][0][L << 3]);
      }
#pragma unroll
      for (int it = 0; it < 4; ++it) {
        int L = it * 256 + tid;
        int row = L >> 3, cc = L & 7;
        int off = k0 + ((cc ^ (row & 7)) << 3);
        gload16(wh + (size_t)(nbase + row) * DIM + off, &lds[buf][1][L << 3]);
      }
    };
    auto frag = [&](const short* b, int row, int kc) -> bf16x8 {
      return *(const bf16x8*)(b + row * 64 + ((kc ^ (row & 7)) << 3));
    };
    auto compute = [&](int buf) {
      const short* As = lds[buf][0];
      const short* Bs = lds[buf][1];
      const int r0 = wr * 64 + l31, r1 = r0 + 32;
      const int cc0 = wc * 64 + l31, cc1 = cc0 + 32;
#pragma unroll
      for (int ks = 0; ks < 4; ++ks) {
        const int kc = ks * 2 + half;
        bf16x8 a0 = frag(As, r0, kc), a1 = frag(As, r1, kc);
        bf16x8 b0 = frag(Bs, cc0, kc), b1 = frag(Bs, cc1, kc);
        acc00 = __builtin_amdgcn_mfma_f32_32x32x16_bf16(a0, b0, acc00, 0, 0, 0);
        acc01 = __builtin_amdgcn_mfma_f32_32x32x16_bf16(a0, b1, acc01, 0, 0, 0);
        acc10 = __builtin_amdgcn_mfma_f32_32x32x16_bf16(a1, b0, acc10, 0, 0, 0);
        acc11 = __builtin_amdgcn_mfma_f32_32x32x16_bf16(a1, b1, acc11, 0, 0, 0);
      }
    };
    stage(0, 0);
    __syncthreads();
    for (int kt = 0; kt < 4; ++kt) {
      const int cur = kt & 1;
      if (kt < 3) stage(cur ^ 1, kt + 1);
      compute(cur);
      __syncthreads();
    }
    // emit candidate codes (duplicates from tail padding are benign)
    auto epi = [&](int mf, const f32x16& A0, const f32x16& A1) {
#pragma unroll
      for (int reg = 0; reg < 16; ++reg) {
        int rl = wr * 64 + mf * 32 + (reg & 3) + ((reg >> 2) << 3) + (half << 2);
        int t = ids[rl];
        float xs = sums[t], th = thr[t];
        float d0 = fmaf(-2.f, A0[reg], xs) + wq0;
        float d1 = fmaf(-2.f, A1[reg], xs) + wq1;
        if (d0 <= th) {
          int pos = atomicAdd(paircnt, 1);
          if (pos < PAIR_CAP) pairs[pos] = ((unsigned)t << 12) | (unsigned)c0;
        }
        if (d1 <= th) {
          int pos = atomicAdd(paircnt, 1);
          if (pos < PAIR_CAP) pairs[pos] = ((unsigned)t << 12) | (unsigned)c1;
        }
      }
    };
    epi(0, acc00, acc01);
    epi(1, acc10, acc11);
  }
}

// ------- pass 2b: exact sequential f32 dot per pair (validated order) -------
__global__ __launch_bounds__(256) void vq_dots(
    const float* __restrict__ X, const float* __restrict__ W,
    const float* __restrict__ sums, const unsigned int* __restrict__ pairs,
    const int* __restrict__ paircnt, unsigned long long* __restrict__ win) {
  const int n = min(*paircnt, PAIR_CAP);
  for (int i = blockIdx.x * 256 + threadIdx.x; i < n; i += gridDim.x * 256) {
    unsigned p = pairs[i];
    int t = p >> 12, c = p & 4095;
    const float4* xr = (const float4*)(X + (size_t)t * DIM);
    const float4* wr = (const float4*)(W + (size_t)c * DIM);
    float acc = 0.f;
#pragma unroll 16
    for (int q = 0; q < 64; ++q) {  // k = 0..255 sequential, == round-2 core
      float4 a = xr[q], b = wr[q];
      acc = fmaf(a.x, b.x, acc);
      acc = fmaf(a.y, b.y, acc);
      acc = fmaf(a.z, b.z, acc);
      acc = fmaf(a.w, b.w, acc);
    }
    float d2 = fmaf(-2.f, acc, sums[t]) + sums[NTOK + c];
    unsigned long long pk =
        ((unsigned long long)__float_as_uint(d2) << 32) | (unsigned)c;
    atomicMin(&win[t], pk);
  }
}

// ---------------- output + loss partials ----------------
__global__ __launch_bounds__(256) void vq_out(
    const float* __restrict__ X, const float* __restrict__ W,
    const unsigned long long* __restrict__ winner, float* __restrict__ out,
    double* __restrict__ lpart) {
  const int tid = threadIdx.x;
  const int wave = tid >> 6, lane = tid & 63;
  const int t = blockIdx.x * 4 + wave;
  const unsigned idx = (unsigned)(winner[t] & 0xFFFFFFFFull);
  float4 xv = ((const float4*)(X + (size_t)t * DIM))[lane];
  float4 qv = ((const float4*)(W + (size_t)idx * DIM))[lane];
  float dx = qv.x - xv.x, dy = qv.y - xv.y, dz = qv.z - xv.z, dw = qv.w - xv.w;
  float4 o;
  o.x = xv.x + dx; o.y = xv.y + dy; o.z = xv.z + dz; o.w = xv.w + dw;
  ((float4*)(out + (size_t)t * DIM))[lane] = o;
  float ls = dx * dx + dy * dy + dz * dz + dw * dw;
#pragma unroll
  for (int m = 1; m < 64; m <<= 1) ls += __shfl_xor(ls, m, 64);
  __shared__ float wsum[4];
  if (lane == 0) wsum[wave] = ls;
  __syncthreads();
  if (tid == 0)
    lpart[blockIdx.x] =
        (double)wsum[0] + (double)wsum[1] + (double)wsum[2] + (double)wsum[3];
}

__global__ __launch_bounds__(256) void vq_loss(const double* __restrict__ lpart,
                                               float* __restrict__ out) {
  const int tid = threadIdx.x;
  double s = 0.0;
#pragma unroll
  for (int k = 0; k < 32; ++k) s += lpart[tid + 256 * k];
#pragma unroll
  for (int m = 1; m < 64; m <<= 1) s += __shfl_xor(s, m, 64);
  __shared__ double ws4[4];
  if ((tid & 63) == 0) ws4[tid >> 6] = s;
  __syncthreads();
  if (tid == 0)
    out[(size_t)NTOK * DIM] =
        (float)((ws4[0] + ws4[1] + ws4[2] + ws4[3]) * (1.25 / 8388608.0));
}

// ============ fallback path (round-2 validated f32 kernels) ============
__global__ __launch_bounds__(256, 2) void vq_main_f32(
    const float* __restrict__ X, const float* __restrict__ W,
    const float* __restrict__ sums, float2* __restrict__ part) {
  __shared__ float lds[2][2][128 * 32];
  const int tid = threadIdx.x;
  const int nblk = blockIdx.x & (NT - 1);
  const int mbase = (blockIdx.x >> 5) * 128, nbase = nblk * 128;
  const int tx = tid & 15, ty = tid >> 4;
  float acc[8][8];
#pragma unroll
  for (int r = 0; r < 8; ++r)
#pragma unroll
    for (int c = 0; c < 8; ++c) acc[r][c] = 0.f;
  auto stage = [&](int buf, int kt) {
#pragma unroll
    for (int it = 0; it < 4; ++it) {
      int L16 = it * 256 + tid;
      int row = L16 >> 3;
      int sch = (L16 & 7) ^ ((row >> 3) & 7);
      gload16(X + (size_t)(mbase + row) * DIM + kt * 32 + sch * 4,
              &lds[buf][0][L16 * 4]);
    }
#pragma unroll
    for (int it = 0; it < 4; ++it) {
      int L16 = it * 256 + tid;
      int row = L16 >> 3;
      int sch = (L16 & 7) ^ ((row >> 3) & 7);
      gload16(W + (size_t)(nbase + row) * DIM + kt * 32 + sch * 4,
              &lds[buf][1][L16 * 4]);
    }
  };
  stage(0, 0);
  __syncthreads();
  for (int kt = 0; kt < 8; ++kt) {
    const int cur = kt & 1;
    if (kt < 7) stage(cur ^ 1, kt + 1);
    const float* Ab = lds[cur][0];
    const float* Bb = lds[cur][1];
#pragma unroll
    for (int k4 = 0; k4 < 8; ++k4) {
      float4 a[8], b[8];
#pragma unroll
      for (int r = 0; r < 8; ++r)
        a[r] = *(const float4*)(Ab + (ty * 8 + r) * 32 + ((k4 ^ (ty & 7)) << 2));
#pragma unroll
      for (int c = 0; c < 8; ++c)
        b[c] = *(const float4*)(Bb + (tx * 8 + c) * 32 + ((k4 ^ (tx & 7)) << 2));
#pragma unroll
      for (int r = 0; r < 8; ++r)
#pragma unroll
        for (int c = 0; c < 8; ++c) {
          acc[r][c] = fmaf(a[r].x, b[c].x, acc[r][c]);
          acc[r][c] = fmaf(a[r].y, b[c].y, acc[r][c]);
          acc[r][c] = fmaf(a[r].z, b[c].z, acc[r][c]);
          acc[r][c] = fmaf(a[r].w, b[c].w, acc[r][c]);
        }
    }
    __syncthreads();
  }
  float xs[8], wq[8];
#pragma unroll
  for (int r = 0; r < 8; ++r) xs[r] = sums[mbase + ty * 8 + r];
#pragma unroll
  for (int c = 0; c < 8; ++c) wq[c] = sums[NTOK + nbase + tx * 8 + c];
#pragma unroll
  for (int r = 0; r < 8; ++r) {
    float bv = INFINITY;
    int bi = 0x7fffffff;
#pragma unroll
    for (int c = 0; c < 8; ++c) {
      float d2 = fmaf(-2.f, acc[r][c], xs[r]) + wq[c];
      int gi = nbase + tx * 8 + c;
      if (d2 < bv) { bv = d2; bi = gi; }
    }
#pragma unroll
    for (int m = 1; m <= 8; m <<= 1) {
      float ov = __shfl_xor(bv, m, 64);
      int oi = __shfl_xor(bi, m, 64);
      if (ov < bv || (ov == bv && oi < bi)) { bv = ov; bi = oi; }
    }
    if (tx == 0)
      part[(size_t)(mbase + ty * 8 + r) * NT + nblk] =
          make_float2(bv, __int_as_float(bi));
  }
}

__global__ __launch_bounds__(256) void vq_final_f32(
    const float* __restrict__ X, const float* __restrict__ W,
    const float2* __restrict__ part, float* __restrict__ out,
    double* __restrict__ lpart) {
  const int tid = threadIdx.x;
  const int wave = tid >> 6, lane = tid & 63;
  const int t = blockIdx.x * 4 + wave;
  float bv = INFINITY;
  int bi = 0x7fffffff;
  if (lane < NT) {
    float2 c = part[(size_t)t * NT + lane];
    bv = c.x;
    bi = __float_as_int(c.y);
  }
#pragma unroll
  for (int m = 1; m <= 16; m <<= 1) {
    float ov = __shfl_xor(bv, m, 64);
    int oi = __shfl_xor(bi, m, 64);
    if (ov < bv || (ov == bv && oi < bi)) { bv = ov; bi = oi; }
  }
  bi = __shfl(bi, 0, 64);
  float4 xv = ((const float4*)(X + (size_t)t * DIM))[lane];
  float4 qv = ((const float4*)(W + (size_t)bi * DIM))[lane];
  float dx = qv.x - xv.x, dy = qv.y - xv.y, dz = qv.z - xv.z, dw = qv.w - xv.w;
  float4 o;
  o.x = xv.x + dx; o.y = xv.y + dy; o.z = xv.z + dz; o.w = xv.w + dw;
  ((float4*)(out + (size_t)t * DIM))[lane] = o;
  float ls = dx * dx + dy * dy + dz * dz + dw * dw;
#pragma unroll
  for (int m = 1; m < 64; m <<= 1) ls += __shfl_xor(ls, m, 64);
  __shared__ float wsum[4];
  if (lane == 0) wsum[wave] = ls;
  __syncthreads();
  if (tid == 0)
    lpart[blockIdx.x] =
        (double)wsum[0] + (double)wsum[1] + (double)wsum[2] + (double)wsum[3];
}

extern "C" void kernel_launch(void* const* d_in, const int* in_sizes, int n_in,
                              void* d_out, int out_size, void* d_ws,
                              size_t ws_size, hipStream_t stream) {
  const float* X = (const float*)d_in[0];
  const float* W = (const float*)d_in[1];
  float* out = (float*)d_out;
  char* ws = (char*)d_ws;
  if (ws_size >= WS_NEEDED) {
    unsigned short* xh = (unsigned short*)(ws + OFF_XH);
    unsigned short* wh = (unsigned short*)(ws + OFF_WH);
    float* sums = (float*)(ws + OFF_SUMS);
    float* part = (float*)(ws + OFF_PART);
    float* thr = (float*)(ws + OFF_THR);
    int* cnt = (int*)(ws + OFF_CNT);
    int* list = (int*)(ws + OFF_LIST);
    unsigned int* pairs = (unsigned int*)(ws + OFF_PAIRS);
    unsigned long long* win = (unsigned long long*)(ws + OFF_WIN);
    double* lpart = (double*)(ws + OFF_LPART);
    vq_prep<<<(NTOK + NCODE) / 4, 256, 0, stream>>>(X, W, sums, xh, wh, cnt, 1);
    vq_mfma<<<(NTOK / 128) * NT, 256, 0, stream>>>(xh, wh, sums, part);
    vq_cand<<<NTOK / 256, 256, 0, stream>>>(part, sums, thr, cnt, list, win);
    vq_exact2<<<NT * 32, 256, 0, stream>>>(xh, wh, sums, thr, cnt, list, pairs,
                                           cnt + NT);
    vq_dots<<<512, 256, 0, stream>>>(X, W, sums, pairs, cnt + NT, win);
    vq_out<<<NTOK / 4, 256, 0, stream>>>(X, W, win, out, lpart);
    vq_loss<<<1, 256, 0, stream>>>(lpart, out);
  } else {
    float* sums = (float*)(ws + OFF_SUMS_O);
    float2* part = (float2*)(ws + OFF_PART_O);
    double* lpart = (double*)(ws + OFF_LPART_O);
    vq_prep<<<(NTOK + NCODE) / 4, 256, 0, stream>>>(X, W, sums, nullptr,
                                                    nullptr, nullptr, 0);
    vq_main_f32<<<(NTOK / 128) * NT, 256, 0, stream>>>(X, W, sums, part);
    vq_final_f32<<<NTOK / 4, 256, 0, stream>>>(X, W, part, out, lpart);
    vq_loss<<<1, 256, 0, stream>>>(lpart, out);
  }
}

// Round 8
// 575.882 us; speedup vs baseline: 2.7070x; 2.7070x over previous
//
#include <hip/hip_runtime.h>
#include <hip/hip_bf16.h>
#include <math.h>

// VectorQuantizer: X[32768,256] f32, W[4096,256] f32
// out = [quantized_st (32768*256 f32), loss (1 f32)]
// Pass 1: bf16 MFMA GEMM (Xh.Wh) -> per-(token,tile) d2' min
// Cand:   per-token thr = gmin' + (sqrt(x_sq)*7e-5 + 3.2e-4)  [>= 2E rigorous]
// Pass 2a (vq_exact2): gathered bf16 MFMA on candidate tiles, emit per-CODE
//          pairs with d2' <= thr via LDS-batched two-phase emission
//          (round-7 lesson: per-hit global atomics to one address = 1 ms stall)
// Pass 2b (vq_dots): exact sequential f32 dot per pair (validated rounding),
//          packed atomicMin winner (min d2, then lowest index)
#define NTOK 32768
#define NCODE 4096
#define DIM 256
#define NT 32        // code tiles of 128
#define PAIR_CAP 2300000
#define LCAP 2048    // per-block LDS emission buffer

typedef short bf16x8 __attribute__((ext_vector_type(8)));
typedef float f32x16 __attribute__((ext_vector_type(16)));

// ---- big-ws layout (bytes), total 37,069,440 ----
#define OFF_XH 0u            // bf16[32768*256]
#define OFF_WH 16777216u     // bf16[4096*256]
#define OFF_SUMS 18874368u   // f32[36864]
#define OFF_PART 19021824u   // f32[32768][32]
#define OFF_THR 23216128u    // f32[32768]
#define OFF_CNT 23347200u    // int[64]: [0..31] tile counts, [32] paircnt
#define OFF_LIST 23347456u   // int[32][32768]
#define OFF_PAIRS 27541760u  // u32[2,300,000]
#define OFF_WIN 36741760u    // u64[32768] (8-aligned)
#define OFF_LPART 37003904u  // double[8192]
#define WS_NEEDED 37069440ull
// ---- small-ws (fallback, validated round 2) ----
#define OFF_SUMS_O 0u
#define OFF_PART_O 147456u
#define OFF_LPART_O 8536064u

__device__ __forceinline__ void gload16(const void* g, void* l) {
  __builtin_amdgcn_global_load_lds(
      (const __attribute__((address_space(1))) void*)g,
      (__attribute__((address_space(3))) void*)l, 16, 0, 0);
}
__device__ __forceinline__ unsigned short bfh(float f) {
  __hip_bfloat16 h = __float2bfloat16(f);
  return *reinterpret_cast<unsigned short*>(&h);
}

// ---------------- prep: sums (+ bf16 conversion, + zero counters) -----------
__global__ __launch_bounds__(256) void vq_prep(
    const float* __restrict__ X, const float* __restrict__ W,
    float* __restrict__ sums, unsigned short* __restrict__ xh,
    unsigned short* __restrict__ wh, int* __restrict__ cnt, int conv) {
  const int tid = threadIdx.x;
  if (conv && blockIdx.x == 0 && tid < NT + 1) cnt[tid] = 0;
  const int wave = tid >> 6, lane = tid & 63;
  const int row = blockIdx.x * 4 + wave;  // 0..36863
  const bool isx = row < NTOK;
  const float* src = isx ? (X + (size_t)row * DIM)
                         : (W + (size_t)(row - NTOK) * DIM);
  float4 v = reinterpret_cast<const float4*>(src)[lane];
  float s = v.x * v.x + v.y * v.y + v.z * v.z + v.w * v.w;
#pragma unroll
  for (int m = 1; m < 64; m <<= 1) s += __shfl_xor(s, m, 64);
  if (lane == 0) sums[row] = s;
  if (conv) {
    ushort4 hi = make_ushort4(bfh(v.x), bfh(v.y), bfh(v.z), bfh(v.w));
    const int r = isx ? row : row - NTOK;
    unsigned short* dh = isx ? xh : wh;
    ((ushort4*)(dh + (size_t)r * DIM))[lane] = hi;
  }
}

// ---------------- pass 1: bf16 MFMA GEMM (K=256) + per-tile d2' min ---------
__global__ __launch_bounds__(256, 2) void vq_mfma(
    const unsigned short* __restrict__ xh, const unsigned short* __restrict__ wh,
    const float* __restrict__ sums, float* __restrict__ part) {
  __shared__ short lds[2][2][8192];  // [dbuf][A/B][128 rows x 64 bf16] = 64 KB
  const int tid = threadIdx.x;
  const int wave = tid >> 6, lane = tid & 63;
  const int wr = wave >> 1, wc = wave & 1;
  const int half = lane >> 5, l31 = lane & 31;
  const int nblk = blockIdx.x & (NT - 1);
  const int mbase = (blockIdx.x >> 5) * 128, nbase = nblk * 128;

  f32x16 acc00, acc01, acc10, acc11;
#pragma unroll
  for (int i = 0; i < 16; ++i) {
    acc00[i] = 0.f; acc01[i] = 0.f; acc10[i] = 0.f; acc11[i] = 0.f;
  }

  auto stage = [&](int buf, int kt) {
    const int k0 = kt * 64;
#pragma unroll
    for (int it = 0; it < 4; ++it) {
      int L = it * 256 + tid;          // 16B-chunk id 0..1023 (8 chunks/row)
      int row = L >> 3, cc = L & 7;
      int off = k0 + ((cc ^ (row & 7)) << 3);
      gload16(xh + (size_t)(mbase + row) * DIM + off, &lds[buf][0][L << 3]);
    }
#pragma unroll
    for (int it = 0; it < 4; ++it) {
      int L = it * 256 + tid;
      int row = L >> 3, cc = L & 7;
      int off = k0 + ((cc ^ (row & 7)) << 3);
      gload16(wh + (size_t)(nbase + row) * DIM + off, &lds[buf][1][L << 3]);
    }
  };
  auto frag = [&](const short* b, int row, int kc) -> bf16x8 {
    return *(const bf16x8*)(b + row * 64 + ((kc ^ (row & 7)) << 3));
  };
  auto compute = [&](int buf) {
    const short* As = lds[buf][0];
    const short* Bs = lds[buf][1];
    const int r0 = wr * 64 + l31, r1 = r0 + 32;
    const int c0 = wc * 64 + l31, c1 = c0 + 32;
#pragma unroll
    for (int ks = 0; ks < 4; ++ks) {
      const int kc = ks * 2 + half;
      bf16x8 a0 = frag(As, r0, kc), a1 = frag(As, r1, kc);
      bf16x8 b0 = frag(Bs, c0, kc), b1 = frag(Bs, c1, kc);
      acc00 = __builtin_amdgcn_mfma_f32_32x32x16_bf16(a0, b0, acc00, 0, 0, 0);
      acc01 = __builtin_amdgcn_mfma_f32_32x32x16_bf16(a0, b1, acc01, 0, 0, 0);
      acc10 = __builtin_amdgcn_mfma_f32_32x32x16_bf16(a1, b0, acc10, 0, 0, 0);
      acc11 = __builtin_amdgcn_mfma_f32_32x32x16_bf16(a1, b1, acc11, 0, 0, 0);
    }
  };

  stage(0, 0);
  __syncthreads();
  for (int kt = 0; kt < 4; ++kt) {
    const int cur = kt & 1;
    if (kt < 3) stage(cur ^ 1, kt + 1);
    compute(cur);
    __syncthreads();
  }

  float* redm = (float*)lds;  // [128][2]
  const float wq0 = sums[NTOK + nbase + wc * 64 + l31];
  const float wq1 = sums[NTOK + nbase + wc * 64 + l31 + 32];
  auto epi = [&](int mf, const f32x16& A0, const f32x16& A1) {
#pragma unroll
    for (int reg = 0; reg < 16; ++reg) {
      int rl = wr * 64 + mf * 32 + (reg & 3) + ((reg >> 2) << 3) + (half << 2);
      float xs = sums[mbase + rl];
      float d0 = fmaf(-2.f, A0[reg], xs) + wq0;
      float d1 = fmaf(-2.f, A1[reg], xs) + wq1;
      float v = fminf(d0, d1);
#pragma unroll
      for (int m = 1; m <= 16; m <<= 1) v = fminf(v, __shfl_xor(v, m, 64));
      if (l31 == 0) redm[rl * 2 + wc] = v;
    }
  };
  epi(0, acc00, acc01);
  epi(1, acc10, acc11);
  __syncthreads();
  if (tid < 128)
    part[(size_t)(mbase + tid) * NT + nblk] = fminf(redm[tid * 2], redm[tid * 2 + 1]);
}

// ------- cand: per-token thr (rigorous 2E bound) + candidate tiles ----------
__global__ __launch_bounds__(256) void vq_cand(
    const float* __restrict__ part, const float* __restrict__ sums,
    float* __restrict__ thr, int* __restrict__ cnt, int* __restrict__ list,
    unsigned long long* __restrict__ winner) {
  const int t = blockIdx.x * 256 + threadIdx.x;
  const int lane = threadIdx.x & 63;
  const float* p = part + (size_t)t * NT;
  float g = p[0];
#pragma unroll
  for (int i = 1; i < NT; ++i) g = fminf(g, p[i]);
  winner[t] = ~0ull;
  const float th = g + fmaf(sqrtf(sums[t]), 7.0e-5f, 3.2e-4f);
  thr[t] = th;
#pragma unroll 1
  for (int tau = 0; tau < NT; ++tau) {
    bool take = p[tau] <= th;
    unsigned long long mask = __ballot(take);
    if (mask) {
      int leader = __ffsll((unsigned long long)mask) - 1;
      int nw = __popcll(mask);
      int base = 0;
      if (lane == leader) base = atomicAdd(&cnt[tau], nw);
      base = __shfl(base, leader, 64);
      if (take) {
        int pre = __popcll(mask & ((1ull << lane) - 1));
        list[tau * NTOK + base + pre] = t;
      }
    }
  }
}

// ------- pass 2a: gathered bf16 MFMA on candidate tiles, LDS-batched emit ---
__global__ __launch_bounds__(256, 2) void vq_exact2(
    const unsigned short* __restrict__ xh, const unsigned short* __restrict__ wh,
    const float* __restrict__ sums, const float* __restrict__ thr,
    const int* __restrict__ cnt, const int* __restrict__ list,
    unsigned int* __restrict__ pairs, int* __restrict__ paircnt) {
  __shared__ short lds[2][2][8192];
  __shared__ int ids[128];
  __shared__ unsigned lbuf[LCAP];
  __shared__ int lcnt, sgbase;
  const int tid = threadIdx.x;
  const int wave = tid >> 6, lane = tid & 63;
  const int wr = wave >> 1, wc = wave & 1;
  const int half = lane >> 5, l31 = lane & 31;
  const int tau = blockIdx.x >> 5, slot = blockIdx.x & 31;  // 32 slots/tile
  const int count = cnt[tau];
  const int nbase = tau * 128;
  const int c0 = nbase + wc * 64 + l31, c1 = c0 + 32;
  const float wq0 = sums[NTOK + c0], wq1 = sums[NTOK + c1];

  for (int base = slot * 128; base < count; base += 4096) {
    __syncthreads();
    if (tid == 0) lcnt = 0;
    if (tid < 128) ids[tid] = list[tau * NTOK + min(base + tid, count - 1)];
    __syncthreads();
    f32x16 acc00, acc01, acc10, acc11;
#pragma unroll
    for (int i = 0; i < 16; ++i) {
      acc00[i] = 0.f; acc01[i] = 0.f; acc10[i] = 0.f; acc11[i] = 0.f;
    }
    auto stage = [&](int buf, int kt) {
      const int k0 = kt * 64;
#pragma unroll
      for (int it = 0; it < 4; ++it) {
        int L = it * 256 + tid;
        int row = L >> 3, cc = L & 7;
        int off = k0 + ((cc ^ (row & 7)) << 3);
        gload16(xh + (size_t)ids[row] * DIM + off, &lds[buf][0][L << 3]);
      }
#pragma unroll
      for (int it = 0; it < 4; ++it) {
        int L = it * 256 + tid;
        int row = L >> 3, cc = L & 7;
        int off = k0 + ((cc ^ (row & 7)) << 3);
        gload16(wh + (size_t)(nbase + row) * DIM + off, &lds[buf][1][L << 3]);
      }
    };
    auto frag = [&](const short* b, int row, int kc) -> bf16x8 {
      return *(const bf16x8*)(b + row * 64 + ((kc ^ (row & 7)) << 3));
    };
    auto compute = [&](int buf) {
      const short* As = lds[buf][0];
      const short* Bs = lds[buf][1];
      const int r0 = wr * 64 + l31, r1 = r0 + 32;
      const int cc0 = wc * 64 + l31, cc1 = cc0 + 32;
#pragma unroll
      for (int ks = 0; ks < 4; ++ks) {
        const int kc = ks * 2 + half;
        bf16x8 a0 = frag(As, r0, kc), a1 = frag(As, r1, kc);
        bf16x8 b0 = frag(Bs, cc0, kc), b1 = frag(Bs, cc1, kc);
        acc00 = __builtin_amdgcn_mfma_f32_32x32x16_bf16(a0, b0, acc00, 0, 0, 0);
        acc01 = __builtin_amdgcn_mfma_f32_32x32x16_bf16(a0, b1, acc01, 0, 0, 0);
        acc10 = __builtin_amdgcn_mfma_f32_32x32x16_bf16(a1, b0, acc10, 0, 0, 0);
        acc11 = __builtin_amdgcn_mfma_f32_32x32x16_bf16(a1, b1, acc11, 0, 0, 0);
      }
    };
    stage(0, 0);
    __syncthreads();
    for (int kt = 0; kt < 4; ++kt) {
      const int cur = kt & 1;
      if (kt < 3) stage(cur ^ 1, kt + 1);
      compute(cur);
      __syncthreads();
    }
    // emit candidate codes into LDS (block-local atomics), duplicates benign
    auto emit = [&](int t, unsigned c) {
      int lp = atomicAdd(&lcnt, 1);
      unsigned pr = ((unsigned)t << 12) | c;
      if (lp < LCAP) {
        lbuf[lp] = pr;
      } else {  // overflow fallback (rare)
        int gp = atomicAdd(paircnt, 1);
        if (gp < PAIR_CAP) pairs[gp] = pr;
      }
    };
    auto epi = [&](int mf, const f32x16& A0, const f32x16& A1) {
#pragma unroll
      for (int reg = 0; reg < 16; ++reg) {
        int rl = wr * 64 + mf * 32 + (reg & 3) + ((reg >> 2) << 3) + (half << 2);
        int t = ids[rl];
        float xs = sums[t], th = thr[t];
        float d0 = fmaf(-2.f, A0[reg], xs) + wq0;
        float d1 = fmaf(-2.f, A1[reg], xs) + wq1;
        if (d0 <= th) emit(t, (unsigned)c0);
        if (d1 <= th) emit(t, (unsigned)c1);
      }
    };
    epi(0, acc00, acc01);
    epi(1, acc10, acc11);
    __syncthreads();
    const int n = min(lcnt, LCAP);
    if (tid == 0) sgbase = atomicAdd(paircnt, n);  // ONE global atomic/batch
    __syncthreads();
    for (int i = tid; i < n; i += 256) {
      int gp = sgbase + i;
      if (gp < PAIR_CAP) pairs[gp] = lbuf[i];
    }
  }
}

// ------- pass 2b: exact sequential f32 dot per pair (validated order) -------
__global__ __launch_bounds__(256) void vq_dots(
    const float* __restrict__ X, const float* __restrict__ W,
    const float* __restrict__ sums, const unsigned int* __restrict__ pairs,
    const int* __restrict__ paircnt, unsigned long long* __restrict__ win) {
  const int n = min(*paircnt, PAIR_CAP);
  for (int i = blockIdx.x * 256 + threadIdx.x; i < n; i += gridDim.x * 256) {
    unsigned p = pairs[i];
    int t = p >> 12, c = p & 4095;
    const float4* xr = (const float4*)(X + (size_t)t * DIM);
    const float4* wr = (const float4*)(W + (size_t)c * DIM);
    float acc = 0.f;
#pragma unroll 16
    for (int q = 0; q < 64; ++q) {  // k = 0..255 sequential, == round-2 core
      float4 a = xr[q], b = wr[q];
      acc = fmaf(a.x, b.x, acc);
      acc = fmaf(a.y, b.y, acc);
      acc = fmaf(a.z, b.z, acc);
      acc = fmaf(a.w, b.w, acc);
    }
    float d2 = fmaf(-2.f, acc, sums[t]) + sums[NTOK + c];
    unsigned long long pk =
        ((unsigned long long)__float_as_uint(d2) << 32) | (unsigned)c;
    atomicMin(&win[t], pk);
  }
}

// ---------------- output + loss partials ----------------
__global__ __launch_bounds__(256) void vq_out(
    const float* __restrict__ X, const float* __restrict__ W,
    const unsigned long long* __restrict__ winner, float* __restrict__ out,
    double* __restrict__ lpart) {
  const int tid = threadIdx.x;
  const int wave = tid >> 6, lane = tid & 63;
  const int t = blockIdx.x * 4 + wave;
  const unsigned idx = (unsigned)(winner[t] & 0xFFFFFFFFull);
  float4 xv = ((const float4*)(X + (size_t)t * DIM))[lane];
  float4 qv = ((const float4*)(W + (size_t)idx * DIM))[lane];
  float dx = qv.x - xv.x, dy = qv.y - xv.y, dz = qv.z - xv.z, dw = qv.w - xv.w;
  float4 o;
  o.x = xv.x + dx; o.y = xv.y + dy; o.z = xv.z + dz; o.w = xv.w + dw;
  ((float4*)(out + (size_t)t * DIM))[lane] = o;
  float ls = dx * dx + dy * dy + dz * dz + dw * dw;
#pragma unroll
  for (int m = 1; m < 64; m <<= 1) ls += __shfl_xor(ls, m, 64);
  __shared__ float wsum[4];
  if (lane == 0) wsum[wave] = ls;
  __syncthreads();
  if (tid == 0)
    lpart[blockIdx.x] =
        (double)wsum[0] + (double)wsum[1] + (double)wsum[2] + (double)wsum[3];
}

__global__ __launch_bounds__(256) void vq_loss(const double* __restrict__ lpart,
                                               float* __restrict__ out) {
  const int tid = threadIdx.x;
  double s = 0.0;
#pragma unroll
  for (int k = 0; k < 32; ++k) s += lpart[tid + 256 * k];
#pragma unroll
  for (int m = 1; m < 64; m <<= 1) s += __shfl_xor(s, m, 64);
  __shared__ double ws4[4];
  if ((tid & 63) == 0) ws4[tid >> 6] = s;
  __syncthreads();
  if (tid == 0)
    out[(size_t)NTOK * DIM] =
        (float)((ws4[0] + ws4[1] + ws4[2] + ws4[3]) * (1.25 / 8388608.0));
}

// ============ fallback path (round-2 validated f32 kernels) ============
__global__ __launch_bounds__(256, 2) void vq_main_f32(
    const float* __restrict__ X, const float* __restrict__ W,
    const float* __restrict__ sums, float2* __restrict__ part) {
  __shared__ float lds[2][2][128 * 32];
  const int tid = threadIdx.x;
  const int nblk = blockIdx.x & (NT - 1);
  const int mbase = (blockIdx.x >> 5) * 128, nbase = nblk * 128;
  const int tx = tid & 15, ty = tid >> 4;
  float acc[8][8];
#pragma unroll
  for (int r = 0; r < 8; ++r)
#pragma unroll
    for (int c = 0; c < 8; ++c) acc[r][c] = 0.f;
  auto stage = [&](int buf, int kt) {
#pragma unroll
    for (int it = 0; it < 4; ++it) {
      int L16 = it * 256 + tid;
      int row = L16 >> 3;
      int sch = (L16 & 7) ^ ((row >> 3) & 7);
      gload16(X + (size_t)(mbase + row) * DIM + kt * 32 + sch * 4,
              &lds[buf][0][L16 * 4]);
    }
#pragma unroll
    for (int it = 0; it < 4; ++it) {
      int L16 = it * 256 + tid;
      int row = L16 >> 3;
      int sch = (L16 & 7) ^ ((row >> 3) & 7);
      gload16(W + (size_t)(nbase + row) * DIM + kt * 32 + sch * 4,
              &lds[buf][1][L16 * 4]);
    }
  };
  stage(0, 0);
  __syncthreads();
  for (int kt = 0; kt < 8; ++kt) {
    const int cur = kt & 1;
    if (kt < 7) stage(cur ^ 1, kt + 1);
    const float* Ab = lds[cur][0];
    const float* Bb = lds[cur][1];
#pragma unroll
    for (int k4 = 0; k4 < 8; ++k4) {
      float4 a[8], b[8];
#pragma unroll
      for (int r = 0; r < 8; ++r)
        a[r] = *(const float4*)(Ab + (ty * 8 + r) * 32 + ((k4 ^ (ty & 7)) << 2));
#pragma unroll
      for (int c = 0; c < 8; ++c)
        b[c] = *(const float4*)(Bb + (tx * 8 + c) * 32 + ((k4 ^ (tx & 7)) << 2));
#pragma unroll
      for (int r = 0; r < 8; ++r)
#pragma unroll
        for (int c = 0; c < 8; ++c) {
          acc[r][c] = fmaf(a[r].x, b[c].x, acc[r][c]);
          acc[r][c] = fmaf(a[r].y, b[c].y, acc[r][c]);
          acc[r][c] = fmaf(a[r].z, b[c].z, acc[r][c]);
          acc[r][c] = fmaf(a[r].w, b[c].w, acc[r][c]);
        }
    }
    __syncthreads();
  }
  float xs[8], wq[8];
#pragma unroll
  for (int r = 0; r < 8; ++r) xs[r] = sums[mbase + ty * 8 + r];
#pragma unroll
  for (int c = 0; c < 8; ++c) wq[c] = sums[NTOK + nbase + tx * 8 + c];
#pragma unroll
  for (int r = 0; r < 8; ++r) {
    float bv = INFINITY;
    int bi = 0x7fffffff;
#pragma unroll
    for (int c = 0; c < 8; ++c) {
      float d2 = fmaf(-2.f, acc[r][c], xs[r]) + wq[c];
      int gi = nbase + tx * 8 + c;
      if (d2 < bv) { bv = d2; bi = gi; }
    }
#pragma unroll
    for (int m = 1; m <= 8; m <<= 1) {
      float ov = __shfl_xor(bv, m, 64);
      int oi = __shfl_xor(bi, m, 64);
      if (ov < bv || (ov == bv && oi < bi)) { bv = ov; bi = oi; }
    }
    if (tx == 0)
      part[(size_t)(mbase + ty * 8 + r) * NT + nblk] =
          make_float2(bv, __int_as_float(bi));
  }
}

__global__ __launch_bounds__(256) void vq_final_f32(
    const float* __restrict__ X, const float* __restrict__ W,
    const float2* __restrict__ part, float* __restrict__ out,
    double* __restrict__ lpart) {
  const int tid = threadIdx.x;
  const int wave = tid >> 6, lane = tid & 63;
  const int t = blockIdx.x * 4 + wave;
  float bv = INFINITY;
  int bi = 0x7fffffff;
  if (lane < NT) {
    float2 c = part[(size_t)t * NT + lane];
    bv = c.x;
    bi = __float_as_int(c.y);
  }
#pragma unroll
  for (int m = 1; m <= 16; m <<= 1) {
    float ov = __shfl_xor(bv, m, 64);
    int oi = __shfl_xor(bi, m, 64);
    if (ov < bv || (ov == bv && oi < bi)) { bv = ov; bi = oi; }
  }
  bi = __shfl(bi, 0, 64);
  float4 xv = ((const float4*)(X + (size_t)t * DIM))[lane];
  float4 qv = ((const float4*)(W + (size_t)bi * DIM))[lane];
  float dx = qv.x - xv.x, dy = qv.y - xv.y, dz = qv.z - xv.z, dw = qv.w - xv.w;
  float4 o;
  o.x = xv.x + dx; o.y = xv.y + dy; o.z = xv.z + dz; o.w = xv.w + dw;
  ((float4*)(out + (size_t)t * DIM))[lane] = o;
  float ls = dx * dx + dy * dy + dz * dz + dw * dw;
#pragma unroll
  for (int m = 1; m < 64; m <<= 1) ls += __shfl_xor(ls, m, 64);
  __shared__ float wsum[4];
  if (lane == 0) wsum[wave] = ls;
  __syncthreads();
  if (tid == 0)
    lpart[blockIdx.x] =
        (double)wsum[0] + (double)wsum[1] + (double)wsum[2] + (double)wsum[3];
}

extern "C" void kernel_launch(void* const* d_in, const int* in_sizes, int n_in,
                              void* d_out, int out_size, void* d_ws,
                              size_t ws_size, hipStream_t stream) {
  const float* X = (const float*)d_in[0];
  const float* W = (const float*)d_in[1];
  float* out = (float*)d_out;
  char* ws = (char*)d_ws;
  if (ws_size >= WS_NEEDED) {
    unsigned short* xh = (unsigned short*)(ws + OFF_XH);
    unsigned short* wh = (unsigned short*)(ws + OFF_WH);
    float* sums = (float*)(ws + OFF_SUMS);
    float* part = (float*)(ws + OFF_PART);
    float* thr = (float*)(ws + OFF_THR);
    int* cnt = (int*)(ws + OFF_CNT);
    int* list = (int*)(ws + OFF_LIST);
    unsigned int* pairs = (unsigned int*)(ws + OFF_PAIRS);
    unsigned long long* win = (unsigned long long*)(ws + OFF_WIN);
    double* lpart = (double*)(ws + OFF_LPART);
    vq_prep<<<(NTOK + NCODE) / 4, 256, 0, stream>>>(X, W, sums, xh, wh, cnt, 1);
    vq_mfma<<<(NTOK / 128) * NT, 256, 0, stream>>>(xh, wh, sums, part);
    vq_cand<<<NTOK / 256, 256, 0, stream>>>(part, sums, thr, cnt, list, win);
    vq_exact2<<<NT * 32, 256, 0, stream>>>(xh, wh, sums, thr, cnt, list, pairs,
                                           cnt + NT);
    vq_dots<<<512, 256, 0, stream>>>(X, W, sums, pairs, cnt + NT, win);
    vq_out<<<NTOK / 4, 256, 0, stream>>>(X, W, win, out, lpart);
    vq_loss<<<1, 256, 0, stream>>>(lpart, out);
  } else {
    float* sums = (float*)(ws + OFF_SUMS_O);
    float2* part = (float2*)(ws + OFF_PART_O);
    double* lpart = (double*)(ws + OFF_LPART_O);
    vq_prep<<<(NTOK + NCODE) / 4, 256, 0, stream>>>(X, W, sums, nullptr,
                                                    nullptr, nullptr, 0);
    vq_main_f32<<<(NTOK / 128) * NT, 256, 0, stream>>>(X, W, sums, part);
    vq_final_f32<<<NTOK / 4, 256, 0, stream>>>(X, W, part, out, lpart);
    vq_loss<<<1, 256, 0, stream>>>(lpart, out);
  }
}

// Round 11
// 503.001 us; speedup vs baseline: 3.0992x; 1.1449x over previous
//
#include <hip/hip_runtime.h>
#include <hip/hip_bf16.h>
#include <math.h>

// VectorQuantizer: X[32768,256] f32, W[4096,256] f32
// out = [quantized_st (32768*256 f32), loss (1 f32)]
// Pass 1: bf16 MFMA GEMM (Xh.Wh, BK=32, 4 blocks/CU) -> per-(token,tile) d2' min
// Cand:   per-token thr = gmin' + (sqrt(x_sq)*7e-5 + 3.2e-4)  [>= 2E rigorous]
// Pass 2a: gathered bf16 MFMA on candidate tiles, LDS-batched pair emission
// Pass 2b: exact sequential f32 dot per pair, packed atomicMin winner
#define NTOK 32768
#define NCODE 4096
#define DIM 256
#define NT 32        // code tiles of 128
#define PAIR_CAP 2300000
#define LCAP 2048    // per-block LDS emission buffer

typedef short bf16x8 __attribute__((ext_vector_type(8)));
typedef float f32x16 __attribute__((ext_vector_type(16)));

// ---- big-ws layout (bytes), total 37,069,440 ----
#define OFF_XH 0u            // bf16[32768*256]
#define OFF_WH 16777216u     // bf16[4096*256]
#define OFF_SUMS 18874368u   // f32[36864]
#define OFF_PART 19021824u   // f32[NT][NTOK]  (transposed: coalesced both sides)
#define OFF_THR 23216128u    // f32[32768]
#define OFF_CNT 23347200u    // int[64]: [0..31] tile counts, [32] paircnt
#define OFF_LIST 23347456u   // int[32][32768]
#define OFF_PAIRS 27541760u  // u32[2,300,000]
#define OFF_WIN 36741760u    // u64[32768] (8-aligned)
#define OFF_LPART 37003904u  // double[8192]
#define WS_NEEDED 37069440ull
// ---- small-ws (fallback, validated round 2) ----
#define OFF_SUMS_O 0u
#define OFF_PART_O 147456u
#define OFF_LPART_O 8536064u

__device__ __forceinline__ void gload16(const void* g, void* l) {
  __builtin_amdgcn_global_load_lds(
      (const __attribute__((address_space(1))) void*)g,
      (__attribute__((address_space(3))) void*)l, 16, 0, 0);
}
__device__ __forceinline__ unsigned short bfh(float f) {
  __hip_bfloat16 h = __float2bfloat16(f);
  return *reinterpret_cast<unsigned short*>(&h);
}

// ---------------- prep: sums (+ bf16 conversion, + zero counters) -----------
__global__ __launch_bounds__(256) void vq_prep(
    const float* __restrict__ X, const float* __restrict__ W,
    float* __restrict__ sums, unsigned short* __restrict__ xh,
    unsigned short* __restrict__ wh, int* __restrict__ cnt, int conv) {
  const int tid = threadIdx.x;
  if (conv && blockIdx.x == 0 && tid < NT + 1) cnt[tid] = 0;
  const int wave = tid >> 6, lane = tid & 63;
  const int row = blockIdx.x * 4 + wave;  // 0..36863
  const bool isx = row < NTOK;
  const float* src = isx ? (X + (size_t)row * DIM)
                         : (W + (size_t)(row - NTOK) * DIM);
  float4 v = reinterpret_cast<const float4*>(src)[lane];
  float s = v.x * v.x + v.y * v.y + v.z * v.z + v.w * v.w;
#pragma unroll
  for (int m = 1; m < 64; m <<= 1) s += __shfl_xor(s, m, 64);
  if (lane == 0) sums[row] = s;
  if (conv) {
    ushort4 hi = make_ushort4(bfh(v.x), bfh(v.y), bfh(v.z), bfh(v.w));
    const int r = isx ? row : row - NTOK;
    unsigned short* dh = isx ? xh : wh;
    ((ushort4*)(dh + (size_t)r * DIM))[lane] = hi;
  }
}

// ------- pass 1: bf16 MFMA GEMM (K=256, BK=32, 32KB LDS, 4 blk/CU) ----------
__global__ __launch_bounds__(256, 4) void vq_mfma(
    const unsigned short* __restrict__ xh, const unsigned short* __restrict__ wh,
    const float* __restrict__ sums, float* __restrict__ part) {
  __shared__ short lds[2][2][4096];  // [dbuf][A/B][128 rows x 32 bf16] = 32 KB
  const int tid = threadIdx.x;
  const int wave = tid >> 6, lane = tid & 63;
  const int wr = wave >> 1, wc = wave & 1;
  const int half = lane >> 5, l31 = lane & 31;
  // XCD-aware bijective swizzle (8192 % 8 == 0): each XCD gets 1024
  // consecutive logical blocks = 32 A-panels x 32 W-tiles -> L2 locality.
  const int bid = ((blockIdx.x & 7) << 10) | (blockIdx.x >> 3);
  const int nblk = bid & (NT - 1);
  const int mbase = (bid >> 5) * 128, nbase = nblk * 128;

  f32x16 acc00, acc01, acc10, acc11;
#pragma unroll
  for (int i = 0; i < 16; ++i) {
    acc00[i] = 0.f; acc01[i] = 0.f; acc10[i] = 0.f; acc11[i] = 0.f;
  }

  // 4 16B-chunks per 32-bf16 row; both-sides XOR swizzle cc ^ ((row>>1)&3)
  auto stage = [&](int buf, int kt) {
    const int k0 = kt * 32;
#pragma unroll
    for (int it = 0; it < 2; ++it) {
      int L = it * 256 + tid;          // chunk id 0..511
      int row = L >> 2, cc = L & 3;
      int off = k0 + ((cc ^ ((row >> 1) & 3)) << 3);
      gload16(xh + (size_t)(mbase + row) * DIM + off, &lds[buf][0][L << 3]);
    }
#pragma unroll
    for (int it = 0; it < 2; ++it) {
      int L = it * 256 + tid;
      int row = L >> 2, cc = L & 3;
      int off = k0 + ((cc ^ ((row >> 1) & 3)) << 3);
      gload16(wh + (size_t)(nbase + row) * DIM + off, &lds[buf][1][L << 3]);
    }
  };
  auto frag = [&](const short* b, int row, int kc) -> bf16x8 {
    return *(const bf16x8*)(b + row * 32 + ((kc ^ ((row >> 1) & 3)) << 3));
  };
  auto compute = [&](int buf) {
    const short* As = lds[buf][0];
    const short* Bs = lds[buf][1];
    const int r0 = wr * 64 + l31, r1 = r0 + 32;
    const int c0 = wc * 64 + l31, c1 = c0 + 32;
#pragma unroll
    for (int ks = 0; ks < 2; ++ks) {
      const int kc = ks * 2 + half;  // lane holds k = kc*8..kc*8+7
      bf16x8 a0 = frag(As, r0, kc), a1 = frag(As, r1, kc);
      bf16x8 b0 = frag(Bs, c0, kc), b1 = frag(Bs, c1, kc);
      acc00 = __builtin_amdgcn_mfma_f32_32x32x16_bf16(a0, b0, acc00, 0, 0, 0);
      acc01 = __builtin_amdgcn_mfma_f32_32x32x16_bf16(a0, b1, acc01, 0, 0, 0);
      acc10 = __builtin_amdgcn_mfma_f32_32x32x16_bf16(a1, b0, acc10, 0, 0, 0);
      acc11 = __builtin_amdgcn_mfma_f32_32x32x16_bf16(a1, b1, acc11, 0, 0, 0);
    }
  };

  stage(0, 0);
  __syncthreads();
  for (int kt = 0; kt < 8; ++kt) {
    const int cur = kt & 1;
    if (kt < 7) stage(cur ^ 1, kt + 1);
    compute(cur);
    __syncthreads();
  }

  float* redm = (float*)lds;  // [128][2]
  const float wq0 = sums[NTOK + nbase + wc * 64 + l31];
  const float wq1 = sums[NTOK + nbase + wc * 64 + l31 + 32];
  auto epi = [&](int mf, const f32x16& A0, const f32x16& A1) {
#pragma unroll
    for (int reg = 0; reg < 16; ++reg) {
      int rl = wr * 64 + mf * 32 + (reg & 3) + ((reg >> 2) << 3) + (half << 2);
      float xs = sums[mbase + rl];
      float d0 = fmaf(-2.f, A0[reg], xs) + wq0;
      float d1 = fmaf(-2.f, A1[reg], xs) + wq1;
      float v = fminf(d0, d1);
#pragma unroll
      for (int m = 1; m <= 16; m <<= 1) v = fminf(v, __shfl_xor(v, m, 64));
      if (l31 == 0) redm[rl * 2 + wc] = v;
    }
  };
  epi(0, acc00, acc01);
  epi(1, acc10, acc11);
  __syncthreads();
  if (tid < 128)  // transposed, coalesced write
    part[(size_t)nblk * NTOK + mbase + tid] =
        fminf(redm[tid * 2], redm[tid * 2 + 1]);
}

// ------- cand: per-token thr (rigorous 2E bound) + candidate tiles ----------
__global__ __launch_bounds__(256) void vq_cand(
    const float* __restrict__ part, const float* __restrict__ sums,
    float* __restrict__ thr, int* __restrict__ cnt, int* __restrict__ list,
    unsigned long long* __restrict__ winner) {
  const int t = blockIdx.x * 256 + threadIdx.x;
  const int lane = threadIdx.x & 63;
  float g = part[t];  // tau = 0
#pragma unroll 1
  for (int i = 1; i < NT; ++i) g = fminf(g, part[(size_t)i * NTOK + t]);
  winner[t] = ~0ull;
  const float th = g + fmaf(sqrtf(sums[t]), 7.0e-5f, 3.2e-4f);
  thr[t] = th;
#pragma unroll 1
  for (int tau = 0; tau < NT; ++tau) {
    bool take = part[(size_t)tau * NTOK + t] <= th;  // L2-hot re-read
    unsigned long long mask = __ballot(take);
    if (mask) {
      int leader = __ffsll((unsigned long long)mask) - 1;
      int nw = __popcll(mask);
      int base = 0;
      if (lane == leader) base = atomicAdd(&cnt[tau], nw);
      base = __shfl(base, leader, 64);
      if (take) {
        int pre = __popcll(mask & ((1ull << lane) - 1));
        list[tau * NTOK + base + pre] = t;
      }
    }
  }
}

// ------- pass 2a: gathered bf16 MFMA on candidate tiles, LDS-batched emit ---
__global__ __launch_bounds__(256, 2) void vq_exact2(
    const unsigned short* __restrict__ xh, const unsigned short* __restrict__ wh,
    const float* __restrict__ sums, const float* __restrict__ thr,
    const int* __restrict__ cnt, const int* __restrict__ list,
    unsigned int* __restrict__ pairs, int* __restrict__ paircnt) {
  __shared__ short lds[2][2][8192];
  __shared__ int ids[128];
  __shared__ unsigned lbuf[LCAP];
  __shared__ int lcnt, sgbase;
  const int tid = threadIdx.x;
  const int wave = tid >> 6, lane = tid & 63;
  const int wr = wave >> 1, wc = wave & 1;
  const int half = lane >> 5, l31 = lane & 31;
  const int tau = blockIdx.x >> 5, slot = blockIdx.x & 31;  // 32 slots/tile
  const int count = cnt[tau];
  const int nbase = tau * 128;
  const int c0 = nbase + wc * 64 + l31, c1 = c0 + 32;
  const float wq0 = sums[NTOK + c0], wq1 = sums[NTOK + c1];

  for (int base = slot * 128; base < count; base += 4096) {
    __syncthreads();
    if (tid == 0) lcnt = 0;
    if (tid < 128) ids[tid] = list[tau * NTOK + min(base + tid, count - 1)];
    __syncthreads();
    f32x16 acc00, acc01, acc10, acc11;
#pragma unroll
    for (int i = 0; i < 16; ++i) {
      acc00[i] = 0.f; acc01[i] = 0.f; acc10[i] = 0.f; acc11[i] = 0.f;
    }
    auto stage = [&](int buf, int kt) {
      const int k0 = kt * 64;
#pragma unroll
      for (int it = 0; it < 4; ++it) {
        int L = it * 256 + tid;
        int row = L >> 3, cc = L & 7;
        int off = k0 + ((cc ^ (row & 7)) << 3);
        gload16(xh + (size_t)ids[row] * DIM + off, &lds[buf][0][L << 3]);
      }
#pragma unroll
      for (int it = 0; it < 4; ++it) {
        int L = it * 256 + tid;
        int row = L >> 3, cc = L & 7;
        int off = k0 + ((cc ^ (row & 7)) << 3);
        gload16(wh + (size_t)(nbase + row) * DIM + off, &lds[buf][1][L << 3]);
      }
    };
    auto frag = [&](const short* b, int row, int kc) -> bf16x8 {
      return *(const bf16x8*)(b + row * 64 + ((kc ^ (row & 7)) << 3));
    };
    auto compute = [&](int buf) {
      const short* As = lds[buf][0];
      const short* Bs = lds[buf][1];
      const int r0 = wr * 64 + l31, r1 = r0 + 32;
      const int cc0 = wc * 64 + l31, cc1 = cc0 + 32;
#pragma unroll
      for (int ks = 0; ks < 4; ++ks) {
        const int kc = ks * 2 + half;
        bf16x8 a0 = frag(As, r0, kc), a1 = frag(As, r1, kc);
        bf16x8 b0 = frag(Bs, cc0, kc), b1 = frag(Bs, cc1, kc);
        acc00 = __builtin_amdgcn_mfma_f32_32x32x16_bf16(a0, b0, acc00, 0, 0, 0);
        acc01 = __builtin_amdgcn_mfma_f32_32x32x16_bf16(a0, b1, acc01, 0, 0, 0);
        acc10 = __builtin_amdgcn_mfma_f32_32x32x16_bf16(a1, b0, acc10, 0, 0, 0);
        acc11 = __builtin_amdgcn_mfma_f32_32x32x16_bf16(a1, b1, acc11, 0, 0, 0);
      }
    };
    stage(0, 0);
    __syncthreads();
    for (int kt = 0; kt < 4; ++kt) {
      const int cur = kt & 1;
      if (kt < 3) stage(cur ^ 1, kt + 1);
      compute(cur);
      __syncthreads();
    }
    auto emit = [&](int t, unsigned c) {
      int lp = atomicAdd(&lcnt, 1);
      unsigned pr = ((unsigned)t << 12) | c;
      if (lp < LCAP) {
        lbuf[lp] = pr;
      } else {  // overflow fallback (rare)
        int gp = atomicAdd(paircnt, 1);
        if (gp < PAIR_CAP) pairs[gp] = pr;
      }
    };
    auto epi = [&](int mf, const f32x16& A0, const f32x16& A1) {
#pragma unroll
      for (int reg = 0; reg < 16; ++reg) {
        int rl = wr * 64 + mf * 32 + (reg & 3) + ((reg >> 2) << 3) + (half << 2);
        int t = ids[rl];
        float xs = sums[t], th = thr[t];
        float d0 = fmaf(-2.f, A0[reg], xs) + wq0;
        float d1 = fmaf(-2.f, A1[reg], xs) + wq1;
        if (d0 <= th) emit(t, (unsigned)c0);
        if (d1 <= th) emit(t, (unsigned)c1);
      }
    };
    epi(0, acc00, acc01);
    epi(1, acc10, acc11);
    __syncthreads();
    const int n = min(lcnt, LCAP);
    if (tid == 0) sgbase = atomicAdd(paircnt, n);  // ONE global atomic/batch
    __syncthreads();
    for (int i = tid; i < n; i += 256) {
      int gp = sgbase + i;
      if (gp < PAIR_CAP) pairs[gp] = lbuf[i];
    }
  }
}

// ------- pass 2b: exact sequential f32 dot per pair (validated order) -------
__global__ __launch_bounds__(256) void vq_dots(
    const float* __restrict__ X, const float* __restrict__ W,
    const float* __restrict__ sums, const unsigned int* __restrict__ pairs,
    const int* __restrict__ paircnt, unsigned long long* __restrict__ win) {
  const int n = min(*paircnt, PAIR_CAP);
  for (int i = blockIdx.x * 256 + threadIdx.x; i < n; i += gridDim.x * 256) {
    unsigned p = pairs[i];
    int t = p >> 12, c = p & 4095;
    const float4* xr = (const float4*)(X + (size_t)t * DIM);
    const float4* wr = (const float4*)(W + (size_t)c * DIM);
    float acc = 0.f;
#pragma unroll 16
    for (int q = 0; q < 64; ++q) {  // k = 0..255 sequential, == round-2 core
      float4 a = xr[q], b = wr[q];
      acc = fmaf(a.x, b.x, acc);
      acc = fmaf(a.y, b.y, acc);
      acc = fmaf(a.z, b.z, acc);
      acc = fmaf(a.w, b.w, acc);
    }
    float d2 = fmaf(-2.f, acc, sums[t]) + sums[NTOK + c];
    unsigned long long pk =
        ((unsigned long long)__float_as_uint(d2) << 32) | (unsigned)c;
    atomicMin(&win[t], pk);
  }
}

// ---------------- output + loss partials ----------------
__global__ __launch_bounds__(256) void vq_out(
    const float* __restrict__ X, const float* __restrict__ W,
    const unsigned long long* __restrict__ winner, float* __restrict__ out,
    double* __restrict__ lpart) {
  const int tid = threadIdx.x;
  const int wave = tid >> 6, lane = tid & 63;
  const int t = blockIdx.x * 4 + wave;
  const unsigned idx = (unsigned)(winner[t] & 0xFFFFFFFFull);
  float4 xv = ((const float4*)(X + (size_t)t * DIM))[lane];
  float4 qv = ((const float4*)(W + (size_t)idx * DIM))[lane];
  float dx = qv.x - xv.x, dy = qv.y - xv.y, dz = qv.z - xv.z, dw = qv.w - xv.w;
  float4 o;
  o.x = xv.x + dx; o.y = xv.y + dy; o.z = xv.z + dz; o.w = xv.w + dw;
  ((float4*)(out + (size_t)t * DIM))[lane] = o;
  float ls = dx * dx + dy * dy + dz * dz + dw * dw;
#pragma unroll
  for (int m = 1; m < 64; m <<= 1) ls += __shfl_xor(ls, m, 64);
  __shared__ float wsum[4];
  if (lane == 0) wsum[wave] = ls;
  __syncthreads();
  if (tid == 0)
    lpart[blockIdx.x] =
        (double)wsum[0] + (double)wsum[1] + (double)wsum[2] + (double)wsum[3];
}

__global__ __launch_bounds__(256) void vq_loss(const double* __restrict__ lpart,
                                               float* __restrict__ out) {
  const int tid = threadIdx.x;
  double s = 0.0;
#pragma unroll
  for (int k = 0; k < 32; ++k) s += lpart[tid + 256 * k];
#pragma unroll
  for (int m = 1; m < 64; m <<= 1) s += __shfl_xor(s, m, 64);
  __shared__ double ws4[4];
  if ((tid & 63) == 0) ws4[tid >> 6] = s;
  __syncthreads();
  if (tid == 0)
    out[(size_t)NTOK * DIM] =
        (float)((ws4[0] + ws4[1] + ws4[2] + ws4[3]) * (1.25 / 8388608.0));
}

// ============ fallback path (round-2 validated f32 kernels) ============
__global__ __launch_bounds__(256, 2) void vq_main_f32(
    const float* __restrict__ X, const float* __restrict__ W,
    const float* __restrict__ sums, float2* __restrict__ part) {
  __shared__ float lds[2][2][128 * 32];
  const int tid = threadIdx.x;
  const int nblk = blockIdx.x & (NT - 1);
  const int mbase = (blockIdx.x >> 5) * 128, nbase = nblk * 128;
  const int tx = tid & 15, ty = tid >> 4;
  float acc[8][8];
#pragma unroll
  for (int r = 0; r < 8; ++r)
#pragma unroll
    for (int c = 0; c < 8; ++c) acc[r][c] = 0.f;
  auto stage = [&](int buf, int kt) {
#pragma unroll
    for (int it = 0; it < 4; ++it) {
      int L16 = it * 256 + tid;
      int row = L16 >> 3;
      int sch = (L16 & 7) ^ ((row >> 3) & 7);
      gload16(X + (size_t)(mbase + row) * DIM + kt * 32 + sch * 4,
              &lds[buf][0][L16 * 4]);
    }
#pragma unroll
    for (int it = 0; it < 4; ++it) {
      int L16 = it * 256 + tid;
      int row = L16 >> 3;
      int sch = (L16 & 7) ^ ((row >> 3) & 7);
      gload16(W + (size_t)(nbase + row) * DIM + kt * 32 + sch * 4,
              &lds[buf][1][L16 * 4]);
    }
  };
  stage(0, 0);
  __syncthreads();
  for (int kt = 0; kt < 8; ++kt) {
    const int cur = kt & 1;
    if (kt < 7) stage(cur ^ 1, kt + 1);
    const float* Ab = lds[cur][0];
    const float* Bb = lds[cur][1];
#pragma unroll
    for (int k4 = 0; k4 < 8; ++k4) {
      float4 a[8], b[8];
#pragma unroll
      for (int r = 0; r < 8; ++r)
        a[r] = *(const float4*)(Ab + (ty * 8 + r) * 32 + ((k4 ^ (ty & 7)) << 2));
#pragma unroll
      for (int c = 0; c < 8; ++c)
        b[c] = *(const float4*)(Bb + (tx * 8 + c) * 32 + ((k4 ^ (tx & 7)) << 2));
#pragma unroll
      for (int r = 0; r < 8; ++r)
#pragma unroll
        for (int c = 0; c < 8; ++c) {
          acc[r][c] = fmaf(a[r].x, b[c].x, acc[r][c]);
          acc[r][c] = fmaf(a[r].y, b[c].y, acc[r][c]);
          acc[r][c] = fmaf(a[r].z, b[c].z, acc[r][c]);
          acc[r][c] = fmaf(a[r].w, b[c].w, acc[r][c]);
        }
    }
    __syncthreads();
  }
  float xs[8], wq[8];
#pragma unroll
  for (int r = 0; r < 8; ++r) xs[r] = sums[mbase + ty * 8 + r];
#pragma unroll
  for (int c = 0; c < 8; ++c) wq[c] = sums[NTOK + nbase + tx * 8 + c];
#pragma unroll
  for (int r = 0; r < 8; ++r) {
    float bv = INFINITY;
    int bi = 0x7fffffff;
#pragma unroll
    for (int c = 0; c < 8; ++c) {
      float d2 = fmaf(-2.f, acc[r][c], xs[r]) + wq[c];
      int gi = nbase + tx * 8 + c;
      if (d2 < bv) { bv = d2; bi = gi; }
    }
#pragma unroll
    for (int m = 1; m <= 8; m <<= 1) {
      float ov = __shfl_xor(bv, m, 64);
      int oi = __shfl_xor(bi, m, 64);
      if (ov < bv || (ov == bv && oi < bi)) { bv = ov; bi = oi; }
    }
    if (tx == 0)
      part[(size_t)(mbase + ty * 8 + r) * NT + nblk] =
          make_float2(bv, __int_as_float(bi));
  }
}

__global__ __launch_bounds__(256) void vq_final_f32(
    const float* __restrict__ X, const float* __restrict__ W,
    const float2* __restrict__ part, float* __restrict__ out,
    double* __restrict__ lpart) {
  const int tid = threadIdx.x;
  const int wave = tid >> 6, lane = tid & 63;
  const int t = blockIdx.x * 4 + wave;
  float bv = INFINITY;
  int bi = 0x7fffffff;
  if (lane < NT) {
    float2 c = part[(size_t)t * NT + lane];
    bv = c.x;
    bi = __float_as_int(c.y);
  }
#pragma unroll
  for (int m = 1; m <= 16; m <<= 1) {
    float ov = __shfl_xor(bv, m, 64);
    int oi = __shfl_xor(bi, m, 64);
    if (ov < bv || (ov == bv && oi < bi)) { bv = ov; bi = oi; }
  }
  bi = __shfl(bi, 0, 64);
  float4 xv = ((const float4*)(X + (size_t)t * DIM))[lane];
  float4 qv = ((const float4*)(W + (size_t)bi * DIM))[lane];
  float dx = qv.x - xv.x, dy = qv.y - xv.y, dz = qv.z - xv.z, dw = qv.w - xv.w;
  float4 o;
  o.x = xv.x + dx; o.y = xv.y + dy; o.z = xv.z + dz; o.w = xv.w + dw;
  ((float4*)(out + (size_t)t * DIM))[lane] = o;
  float ls = dx * dx + dy * dy + dz * dz + dw * dw;
#pragma unroll
  for (int m = 1; m < 64; m <<= 1) ls += __shfl_xor(ls, m, 64);
  __shared__ float wsum[4];
  if (lane == 0) wsum[wave] = ls;
  __syncthreads();
  if (tid == 0)
    lpart[blockIdx.x] =
        (double)wsum[0] + (double)wsum[1] + (double)wsum[2] + (double)wsum[3];
}

extern "C" void kernel_launch(void* const* d_in, const int* in_sizes, int n_in,
                              void* d_out, int out_size, void* d_ws,
                              size_t ws_size, hipStream_t stream) {
  const float* X = (const float*)d_in[0];
  const float* W = (const float*)d_in[1];
  float* out = (float*)d_out;
  char* ws = (char*)d_ws;
  if (ws_size >= WS_NEEDED) {
    unsigned short* xh = (unsigned short*)(ws + OFF_XH);
    unsigned short* wh = (unsigned short*)(ws + OFF_WH);
    float* sums = (float*)(ws + OFF_SUMS);
    float* part = (float*)(ws + OFF_PART);
    float* thr = (float*)(ws + OFF_THR);
    int* cnt = (int*)(ws + OFF_CNT);
    int* list = (int*)(ws + OFF_LIST);
    unsigned int* pairs = (unsigned int*)(ws + OFF_PAIRS);
    unsigned long long* win = (unsigned long long*)(ws + OFF_WIN);
    double* lpart = (double*)(ws + OFF_LPART);
    vq_prep<<<(NTOK + NCODE) / 4, 256, 0, stream>>>(X, W, sums, xh, wh, cnt, 1);
    vq_mfma<<<(NTOK / 128) * NT, 256, 0, stream>>>(xh, wh, sums, part);
    vq_cand<<<NTOK / 256, 256, 0, stream>>>(part, sums, thr, cnt, list, win);
    vq_exact2<<<NT * 32, 256, 0, stream>>>(xh, wh, sums, thr, cnt, list, pairs,
                                           cnt + NT);
    vq_dots<<<512, 256, 0, stream>>>(X, W, sums, pairs, cnt + NT, win);
    vq_out<<<NTOK / 4, 256, 0, stream>>>(X, W, win, out, lpart);
    vq_loss<<<1, 256, 0, stream>>>(lpart, out);
  } else {
    float* sums = (float*)(ws + OFF_SUMS_O);
    float2* part = (float2*)(ws + OFF_PART_O);
    double* lpart = (double*)(ws + OFF_LPART_O);
    vq_prep<<<(NTOK + NCODE) / 4, 256, 0, stream>>>(X, W, sums, nullptr,
                                                    nullptr, nullptr, 0);
    vq_main_f32<<<(NTOK / 128) * NT, 256, 0, stream>>>(X, W, sums, part);
    vq_final_f32<<<NTOK / 4, 256, 0, stream>>>(X, W, part, out, lpart);
    vq_loss<<<1, 256, 0, stream>>>(lpart, out);
  }
}